// Round 10
// baseline (152.609 us; speedup 1.0000x reference)
//
#include <hip/hip_runtime.h>
#include <math.h>

#define BTOT   32768
#define LAT    128
#define H      17
#define G4     68      // 4*H
#define TSTEPS 50
#define NPR    102     // projection rows: 68 (W_ih) + 17 (W_h0) + 17 (W_c0)
#define WQ     32      // k-quarter width (floats)
#define WPAD   36      // Wbuf row stride: 36 mod 32 = 4 -> same-gate rows <=2-way (free)

#define NW     8              // waves per block
#define RPW    3              // rows per wave (51 active lanes of 64)
#define RPB    (NW * RPW)     // 24 rows per block
#define TPB    (NW * 64)      // 512 threads

// fast gates: v_exp_f32 / v_rcp_f32 based, saturation-safe.
// (R9 lesson: recurrence amplifies per-step error ~1e3x over 50 steps ->
//  recurrent math MUST be f32; these f32 forms passed at absmax 0.0039 in R8.)
__device__ __forceinline__ float fsigmoid(float x) {
    float e = __expf(-x);
    return __builtin_amdgcn_rcpf(1.0f + e);
}
// tanh(x) = 1 - 2*rcp(exp(2x)+1); +inf -> 1, -inf -> -1, no divide.
__device__ __forceinline__ float ftanhf(float x) {
    float e = __expf(2.0f * x);
    float t = __builtin_amdgcn_rcpf(e + 1.0f);
    return fmaf(-2.0f, t, 1.0f);
}

// f32 FMA through inline asm: "v" constraints force VGPR residency of W at
// every use (R6 evidence: plain fmaf let the allocator bank W into AGPRs).
#define FMAC(acc, w, h) asm("v_fmac_f32 %0, %1, %2" : "+v"(acc) : "v"(w), "v"(h))

// launch_bounds(512,5): unified VGPR cap = 102. W(68)+state/working(~30) = ~98
// fits as straight VGPRs -> no AGPR banking, ~20 waves/CU (R8 was 120 regs, 34%).
__global__ __launch_bounds__(TPB, 5)
void lstm_fused(const float* __restrict__ x,
                const float* __restrict__ W_h0, const float* __restrict__ b_h0,
                const float* __restrict__ W_c0, const float* __restrict__ b_c0,
                const float* __restrict__ W_ih, const float* __restrict__ W_hh,
                const float* __restrict__ b_ih, const float* __restrict__ b_hh,
                float* __restrict__ out)
{
    __shared__ float x_tile[RPB][132];      // 12.7 KB
    __shared__ float Wbuf[NPR][WPAD];       // 14.7 KB (one k-quarter)
    __shared__ float Wl[G4 * H];            //  4.6 KB (W_hh f32)
    __shared__ float hbuf[NW][RPW][20];     //  1.9 KB (wave-private h rows)

    const int t    = threadIdx.x;
    const int w    = t >> 6;
    const int lane = t & 63;
    const bool active = lane < RPW * H;       // 51
    const int rl = active ? (lane / H) : 0;   // 0..2
    const int j  = active ? (lane % H) : 0;   // 0..16
    const int r  = w * RPW + rl;              // 0..23
    const int grow0 = blockIdx.x * RPB;
    int grow = grow0 + r;
    const bool valid = active && (grow < BTOT);
    if (grow >= BTOT) grow = BTOT - 1;

    // ---- stage x tile (rows clamped) + W_hh; all 512 threads ----
    for (int i = t; i < RPB * 32; i += TPB) {              // 32 float4 per row
        int rr = i >> 5, c = i & 31;
        int gr = grow0 + rr; if (gr >= BTOT) gr = BTOT - 1;
        *(float4*)&x_tile[rr][c * 4] = ((const float4*)(x + (size_t)gr * LAT))[c];
    }
    for (int i = t; i < G4 * H; i += TPB) Wl[i] = W_hh[i];

    // ---- phase 1: projections in FOUR k-quarters of 32 (LDS diet) ----
    float acc[6] = {0.f, 0.f, 0.f, 0.f, 0.f, 0.f};         // i,f,g,o, h0, c0
    const int rows6[6] = { j, 17 + j, 34 + j, 51 + j, 68 + j, 85 + j };
    for (int qh = 0; qh < 4; ++qh) {
        __syncthreads();  // qh=0: x_tile/Wl ready; else WAR on Wbuf
        for (int i = t; i < NPR * 8; i += TPB) {           // 8 float4 per quarter-row
            int row = i >> 3, c4 = (i & 7) * 4;
            const float* src = (row < G4) ? (W_ih + row * LAT)
                             : (row < 85) ? (W_h0 + (row - G4) * LAT)
                                          : (W_c0 + (row - 85) * LAT);
            *(float4*)&Wbuf[row][c4] = *(const float4*)(src + qh * WQ + c4);
        }
        __syncthreads();  // quarter ready

        for (int kb = 0; kb < 8; ++kb) {
            float4 xv = *(const float4*)&x_tile[r][qh * WQ + kb * 4];
#pragma unroll
            for (int s = 0; s < 6; ++s) {
                float4 wv = *(const float4*)&Wbuf[rows6[s]][kb * 4];
                acc[s] = fmaf(xv.x, wv.x, acc[s]);
                acc[s] = fmaf(xv.y, wv.y, acc[s]);
                acc[s] = fmaf(xv.z, wv.z, acc[s]);
                acc[s] = fmaf(xv.w, wv.w, acc[s]);
            }
        }
    }

    const float xgi = acc[0] + b_ih[j]      + b_hh[j];
    const float xgf = acc[1] + b_ih[17 + j] + b_hh[17 + j];
    const float xgg = acc[2] + b_ih[34 + j] + b_hh[34 + j];
    const float xgo = acc[3] + b_ih[51 + j] + b_hh[51 + j];
    float h = acc[4] + b_h0[j];
    float c = acc[5] + b_c0[j];

    // ---- W_hh rows for gates i,f,g,o of element j -> f32 VGPRs ----
    float Wi[H], Wf[H], Wg[H], Wo[H];
#pragma unroll
    for (int k = 0; k < H; ++k) {
        Wi[k] = Wl[(0 * H + j) * H + k];
        Wf[k] = Wl[(1 * H + j) * H + k];
        Wg[k] = Wl[(2 * H + j) * H + k];
        Wo[k] = Wl[(3 * H + j) * H + k];
        asm volatile("" : "+v"(Wi[k]), "+v"(Wf[k]), "+v"(Wg[k]), "+v"(Wo[k]));
    }

    // ---- phase 2: 50-step recurrence, NO barriers (rows are wave-local) ----
    // Stores are delayed one iteration so the global store of h_{t-1} issues
    // in the ds_write -> ds_read gap (free vmem overlap in the serial window).
    float* orow = out + (size_t)grow * (TSTEPS * H) + j;
    for (int tt = 0; tt < TSTEPS; ++tt) {
        if (active) hbuf[w][rl][j] = h;
        if (valid && tt > 0) orow[(tt - 1) * H] = h;   // h_{t-1} store fills the gap

        float ai = xgi, af = xgf, ag = xgg, ao = xgo;
#pragma unroll
        for (int q = 0; q < 4; ++q) {
            float4 h4 = *(const float4*)&hbuf[w][rl][q * 4];
            FMAC(ai, Wi[q * 4 + 0], h4.x);
            FMAC(af, Wf[q * 4 + 0], h4.x);
            FMAC(ag, Wg[q * 4 + 0], h4.x);
            FMAC(ao, Wo[q * 4 + 0], h4.x);
            FMAC(ai, Wi[q * 4 + 1], h4.y);
            FMAC(af, Wf[q * 4 + 1], h4.y);
            FMAC(ag, Wg[q * 4 + 1], h4.y);
            FMAC(ao, Wo[q * 4 + 1], h4.y);
            FMAC(ai, Wi[q * 4 + 2], h4.z);
            FMAC(af, Wf[q * 4 + 2], h4.z);
            FMAC(ag, Wg[q * 4 + 2], h4.z);
            FMAC(ao, Wo[q * 4 + 2], h4.z);
            FMAC(ai, Wi[q * 4 + 3], h4.w);
            FMAC(af, Wf[q * 4 + 3], h4.w);
            FMAC(ag, Wg[q * 4 + 3], h4.w);
            FMAC(ao, Wo[q * 4 + 3], h4.w);
        }
        {
            const float hk = hbuf[w][rl][16];
            FMAC(ai, Wi[16], hk);
            FMAC(af, Wf[16], hk);
            FMAC(ag, Wg[16], hk);
            FMAC(ao, Wo[16], hk);
        }

        const float ig = fsigmoid(ai);
        const float fg = fsigmoid(af);
        const float gv = ftanhf(ag);
        const float og = fsigmoid(ao);
        c = fmaf(fg, c, ig * gv);
        h = og * ftanhf(c);
    }
    if (valid) orow[(TSTEPS - 1) * H] = h;             // final delayed store

}

extern "C" void kernel_launch(void* const* d_in, const int* in_sizes, int n_in,
                              void* d_out, int out_size, void* d_ws, size_t ws_size,
                              hipStream_t stream)
{
    const float* x    = (const float*)d_in[0];
    const float* W_h0 = (const float*)d_in[1];
    const float* b_h0 = (const float*)d_in[2];
    const float* W_c0 = (const float*)d_in[3];
    const float* b_c0 = (const float*)d_in[4];
    const float* W_ih = (const float*)d_in[5];
    const float* W_hh = (const float*)d_in[6];
    const float* b_ih = (const float*)d_in[7];
    const float* b_hh = (const float*)d_in[8];
    float* out = (float*)d_out;

    (void)d_ws; (void)ws_size;  // no workspace used

    const int nblk = (BTOT + RPB - 1) / RPB;   // 1366
    hipLaunchKernelGGL(lstm_fused, dim3(nblk), dim3(TPB), 0, stream,
                       x, W_h0, b_h0, W_c0, b_c0, W_ih, W_hh, b_ih, b_hh, out);
}